// Round 4
// baseline (97.061 us; speedup 1.0000x reference)
//
#include <hip/hip_runtime.h>
#include <hip/hip_bf16.h>

#define FEATN 501
#define KPAD 1024
#define NB 8192
#define NT 512
#define DTC 0.01f

typedef __attribute__((ext_vector_type(8))) short short8;
typedef __attribute__((ext_vector_type(4))) float f32x4;

__device__ __forceinline__ float softplus_f(float x) {
    return fmaxf(x, 0.f) + log1pf(expf(-fabsf(x)));
}
__device__ __forceinline__ ushort f2bf(float x) {
    __hip_bfloat16 h = __float2bfloat16(x);   // RNE
    return *reinterpret_cast<ushort*>(&h);
}
__device__ __forceinline__ void gl_lds16(const void* g, void* l) {
    __builtin_amdgcn_global_load_lds(
        (const __attribute__((address_space(1))) void*)g,
        (__attribute__((address_space(3))) void*)l, 16, 0, 0);
}
// one DPP-add reduction step (pure VALU, no DS)
__device__ __forceinline__ float dpp_add(float x, const int ctrl) {
    int s = __builtin_bit_cast(int, x);
    int y;
    switch (ctrl) {   // ctrl must be a literal constant per call site
    case 0xB1:  y = __builtin_amdgcn_update_dpp(0, s, 0xB1, 0xf, 0xf, true); break;
    case 0x4E:  y = __builtin_amdgcn_update_dpp(0, s, 0x4E, 0xf, 0xf, true); break;
    default:    y = __builtin_amdgcn_update_dpp(0, s, 0x141, 0xf, 0xf, true); break;
    }
    return x + __builtin_bit_cast(float, y);
}

// ---------------- prep: harmonic stats + m -> bf16 (padded) ----------------
__global__ __launch_bounds__(256) void prep_kernel(
    const float* __restrict__ E, const float* __restrict__ nu,
    float* __restrict__ out) {
    const int b = blockIdx.x * 4 + (threadIdx.x >> 6);
    const int lane = threadIdx.x & 63;
    const size_t base = (size_t)b * FEATN;
    float* cb = out + (size_t)NB * NT + (size_t)b * 4096;
    ushort* mb = (ushort*)(cb + 512);
    float s1 = 0.f, s2 = 0.f;
    for (int i = lane; i < FEATN; i += 64) {
        const float Ev = E[base + i];
        const float nv = nu[base + i];
        const float inv = 1.0f / nv;
        s1 += inv;
        s2 = fmaf(Ev, inv * inv, s2);
        mb[i] = f2bf(Ev);
        mb[FEATN + i] = f2bf(nv);
    }
    if (lane < KPAD - 2 * FEATN) mb[2 * FEATN + lane] = 0;   // zero pad
    #pragma unroll
    for (int o = 32; o; o >>= 1) { s1 += __shfl_xor(s1, o); s2 += __shfl_xor(s2, o); }
    if (lane == 0) {
        const float np = (float)FEATN / s1;
        cb[26] = np;
        cb[27] = (s2 / (float)FEATN) * np * np;
    }
}

// ---------------- wtrans: W[1002][64]x2 -> Wt[128][1024] bf16 --------------
__global__ __launch_bounds__(256) void wtrans_kernel(
    const float* __restrict__ Bw1, const float* __restrict__ bw1,
    ushort* __restrict__ Wt) {
    const int h = blockIdx.x;
    const int lane = threadIdx.x & 63;
    const int wv = threadIdx.x >> 6;
    const float* W = (h < 64) ? Bw1 : bw1;
    const int col = h & 63;
    #pragma unroll
    for (int it = 0; it < 4; ++it) {
        const int k = it * 256 + wv * 64 + lane;
        const float v = (k < 2 * FEATN) ? W[(size_t)k * 64 + col] : 0.f;
        Wt[(size_t)h * KPAD + k] = f2bf(v);
    }
}

// ---------------- enc: C[16b x 128h] MFMA GEMM, K=1024 ---------------------
__global__ __launch_bounds__(256) void enc_kernel(
    const ushort* __restrict__ Wt,
    const float* __restrict__ Bb1, const float* __restrict__ bb1,
    const float* __restrict__ Bw2, const float* __restrict__ Bb2,
    const float* __restrict__ bw2, const float* __restrict__ bb2,
    float* __restrict__ out) {
    __shared__ ushort Wl[2][4096];
    __shared__ ushort Ml[2][512];
    __shared__ float hid[128][17];
    const int tid = threadIdx.x;
    const int wv = tid >> 6, lane = tid & 63;
    const int bb0 = blockIdx.x * 16;
    float* xi = out + (size_t)NB * NT;

    const int srow = lane >> 2;
    const int sslot = lane & 3;
    const ushort* mbase = (const ushort*)(xi + (size_t)(bb0 + srow) * 4096 + 512);
    const int n0 = wv * 2;

    auto stage = [&](int s, int buf) {
        const int kb = s * 32;
        gl_lds16(Wt + (size_t)(n0 * 16 + srow) * KPAD + kb + sslot * 8,
                 &Wl[buf][n0 * 512]);
        gl_lds16(Wt + (size_t)(n0 * 16 + 16 + srow) * KPAD + kb + sslot * 8,
                 &Wl[buf][n0 * 512 + 512]);
        if (wv == 3) gl_lds16(mbase + kb + sslot * 8, &Ml[buf][0]);
    };

    const int r15 = lane & 15, kg = lane >> 4;
    const int aoff0 = (wv * 32 + r15) * 32 + kg * 8;
    const int aoff1 = aoff0 + 16 * 32;
    const int boff = r15 * 32 + kg * 8;

    f32x4 acc0 = {0.f, 0.f, 0.f, 0.f}, acc1 = acc0;
    stage(0, 0);
    __syncthreads();
    for (int s = 0; s < 32; ++s) {
        const int buf = s & 1;
        if (s + 1 < 32) stage(s + 1, buf ^ 1);
        short8 a0 = *(const short8*)&Wl[buf][aoff0];
        short8 a1 = *(const short8*)&Wl[buf][aoff1];
        short8 b = *(const short8*)&Ml[buf][boff];
        acc0 = __builtin_amdgcn_mfma_f32_16x16x32_bf16(a0, b, acc0, 0, 0, 0);
        acc1 = __builtin_amdgcn_mfma_f32_16x16x32_bf16(a1, b, acc1, 0, 0, 0);
        __syncthreads();
    }

    #pragma unroll
    for (int t = 0; t < 2; ++t) {
        #pragma unroll
        for (int r = 0; r < 4; ++r) {
            const int h = wv * 32 + t * 16 + kg * 4 + r;
            const float bias = (h < 64) ? Bb1[h] : bb1[h - 64];
            float v = (t ? acc1[r] : acc0[r]) + bias;
            v = (h < 64) ? fmaxf(v, 0.f) : softplus_f(v);
            hid[h][r15] = v;
        }
    }
    __syncthreads();

    if (tid < 128) {
        const int bl = tid >> 3, k = tid & 7;
        float dB = 0.f, db = 0.f;
        #pragma unroll 8
        for (int h = 0; h < 64; ++h) {
            dB = fmaf(hid[h][bl], Bw2[h * 8 + k], dB);
            db = fmaf(hid[64 + h][bl], bw2[h * 8 + k], db);
        }
        const float Bm = dB + Bb2[k];
        const float be = softplus_f(db + bb2[k]);
        float Bs = Bm;
        Bs += __shfl_xor(Bs, 1);
        Bs += __shfl_xor(Bs, 2);
        Bs += __shfl_xor(Bs, 4);
        float* cb = xi + (size_t)(bb0 + bl) * 4096;
        const float np = cb[26];
        const float Ep = cb[27];
        cb[k] = 1.f - DTC * be * (Bm + Bs);
        cb[8 + k] = DTC * be * Bm;
        cb[16 + k] = Bm;
        if (k == 0) { cb[24] = Bs * Ep; cb[25] = np; }
    }
}

// ---------------- time loop (closed-form window + prefetch + DPP) ----------
// grid 2048 x 256: one wave per batch. lane = j*8+k.
// xi(t0+j) = a^j xi(t0) + sum_{i<j} a^(j-1-i) c u_i  -> 8 indep FMA per lane.
__global__ __launch_bounds__(256) void time_kernel(
    const float* __restrict__ e, const float* __restrict__ ed,
    const float* coef, float* stress, float* xi_out) {
    const int wid = (blockIdx.x << 2) + (threadIdx.x >> 6);
    const int lane = threadIdx.x & 63;
    const int j = lane >> 3, k = lane & 7;

    const float* cb = coef + (size_t)wid * 4096;
    const float a = cb[k];
    const float c = cb[8 + k];
    const float Bm = cb[16 + k];
    const float sE = cb[24];
    const float nup = cb[25];
    // coefs live in the buffer this wave overwrites; ensure loads landed
    asm volatile("s_waitcnt vmcnt(0)" ::: "memory");

    // per-lane window constants
    const float a2 = a * a, a4 = a2 * a2;
    const float P = a4 * a4;                 // a^8
    float A = 1.f;                           // a^j
    if (j & 1) A *= a;
    if (j & 2) A *= a2;
    if (j & 4) A *= a4;
    float pw[8];                             // pw[i] = (i<j) ? a^(j-1-i)*c : 0
    {
        float run = c;
        #pragma unroll
        for (int i = 7; i >= 0; --i) {
            const bool on = (i < j);
            pw[i] = on ? run : 0.f;
            run = on ? run * a : run;
        }
    }
    float pv[8];                             // pv[i] = a^(7-i)*c
    pv[7] = c;
    #pragma unroll
    for (int i = 6; i >= 0; --i) pv[i] = a * pv[i + 1];

    const float* eb = e + (size_t)wid * NT;
    const float* edb = ed + (size_t)wid * NT;
    float* xb = xi_out + (size_t)wid * (NT * 8);
    float* sb = stress + (size_t)wid * NT;

    // prefetch window 0
    float4 nu0 = *(const float4*)(eb);
    float4 nu1 = *(const float4*)(eb + 4);
    float nuj = eb[j];
    float npj = edb[j];

    float xs = 0.f;
    for (int t0 = 0; t0 < NT; t0 += 8) {
        const float u0 = nu0.x, u1 = nu0.y, u2 = nu0.z, u3 = nu0.w;
        const float u4 = nu1.x, u5 = nu1.y, u6 = nu1.z, u7 = nu1.w;
        const float cuj = nuj, cpj = npj;
        if (t0 + 8 < NT) {                   // prefetch next window early
            nu0 = *(const float4*)(eb + t0 + 8);
            nu1 = *(const float4*)(eb + t0 + 12);
            nuj = eb[t0 + 8 + j];
            npj = edb[t0 + 8 + j];
        }
        float xi_j = A * xs;
        xi_j = fmaf(pw[0], u0, xi_j);
        xi_j = fmaf(pw[1], u1, xi_j);
        xi_j = fmaf(pw[2], u2, xi_j);
        xi_j = fmaf(pw[3], u3, xi_j);
        xi_j = fmaf(pw[4], u4, xi_j);
        xi_j = fmaf(pw[5], u5, xi_j);
        xi_j = fmaf(pw[6], u6, xi_j);
        xi_j = fmaf(pw[7], u7, xi_j);
        float ns = P * xs;
        ns = fmaf(pv[0], u0, ns);
        ns = fmaf(pv[1], u1, ns);
        ns = fmaf(pv[2], u2, ns);
        ns = fmaf(pv[3], u3, ns);
        ns = fmaf(pv[4], u4, ns);
        ns = fmaf(pv[5], u5, ns);
        ns = fmaf(pv[6], u6, ns);
        ns = fmaf(pv[7], u7, ns);
        xs = ns;
        xb[t0 * 8 + lane] = xi_j;            // coalesced 256B/wave
        float r = Bm * (cuj - xi_j);
        r = dpp_add(r, 0xB1);                // + lane^1
        r = dpp_add(r, 0x4E);                // + lane^2
        r = dpp_add(r, 0x141);               // + other quad (within 8)
        if (k == 0) sb[t0 + j] = fmaf(sE, cuj, fmaf(nup, cpj, r));
    }
}

extern "C" void kernel_launch(void* const* d_in, const int* in_sizes, int n_in,
                              void* d_out, int out_size, void* d_ws, size_t ws_size,
                              hipStream_t stream) {
    const float* e   = (const float*)d_in[0];
    const float* ed  = (const float*)d_in[1];
    const float* E   = (const float*)d_in[2];
    const float* nu  = (const float*)d_in[3];
    const float* Bw1 = (const float*)d_in[4];
    const float* Bb1 = (const float*)d_in[5];
    const float* Bw2 = (const float*)d_in[6];
    const float* Bb2 = (const float*)d_in[7];
    const float* bw1 = (const float*)d_in[8];
    const float* bb1 = (const float*)d_in[9];
    const float* bw2 = (const float*)d_in[10];
    const float* bb2 = (const float*)d_in[11];

    float* out = (float*)d_out;
    float* stress = out;                        // [B*T] floats
    float* xi = out + (size_t)NB * NT;          // [B*T*8] floats
    ushort* Wt = (ushort*)out;                  // 256 KB stash in stress region

    prep_kernel<<<2048, 256, 0, stream>>>(E, nu, out);
    wtrans_kernel<<<128, 256, 0, stream>>>(Bw1, bw1, Wt);
    enc_kernel<<<512, 256, 0, stream>>>(Wt, Bb1, bb1, Bw2, Bb2, bw2, bb2, out);
    time_kernel<<<2048, 256, 0, stream>>>(e, ed, xi, stress, xi);
}

// Round 5
// 70.975 us; speedup vs baseline: 1.3675x; 1.3675x over previous
//
#include <hip/hip_runtime.h>
#include <hip/hip_bf16.h>

#define FEATN 501
#define KPAD 1024
#define NB 8192
#define NT 512
#define DTC 0.01f

typedef __attribute__((ext_vector_type(8))) short short8;
typedef __attribute__((ext_vector_type(4))) float f32x4;

__device__ __forceinline__ float softplus_f(float x) {
    return fmaxf(x, 0.f) + log1pf(expf(-fabsf(x)));
}
__device__ __forceinline__ ushort f2bf(float x) {
    __hip_bfloat16 h = __float2bfloat16(x);   // RNE
    return *reinterpret_cast<ushort*>(&h);
}
__device__ __forceinline__ void gl_lds16(const void* g, void* l) {
    __builtin_amdgcn_global_load_lds(
        (const __attribute__((address_space(1))) void*)g,
        (__attribute__((address_space(3))) void*)l, 16, 0, 0);
}
// one DPP-add reduction step (pure VALU, no DS)
__device__ __forceinline__ float dpp_add(float x, const int ctrl) {
    int s = __builtin_bit_cast(int, x);
    int y;
    switch (ctrl) {   // ctrl must be a literal constant per call site
    case 0xB1:  y = __builtin_amdgcn_update_dpp(0, s, 0xB1, 0xf, 0xf, true); break;
    case 0x4E:  y = __builtin_amdgcn_update_dpp(0, s, 0x4E, 0xf, 0xf, true); break;
    default:    y = __builtin_amdgcn_update_dpp(0, s, 0x141, 0xf, 0xf, true); break;
    }
    return x + __builtin_bit_cast(float, y);
}

// ---------------- prep: harmonic stats + m -> bf16 (padded) ----------------
__global__ __launch_bounds__(256) void prep_kernel(
    const float* __restrict__ E, const float* __restrict__ nu,
    float* __restrict__ out) {
    const int b = blockIdx.x * 4 + (threadIdx.x >> 6);
    const int lane = threadIdx.x & 63;
    const size_t base = (size_t)b * FEATN;
    float* cb = out + (size_t)NB * NT + (size_t)b * 4096;
    ushort* mb = (ushort*)(cb + 512);
    float s1 = 0.f, s2 = 0.f;
    for (int i = lane; i < FEATN; i += 64) {
        const float Ev = E[base + i];
        const float nv = nu[base + i];
        const float inv = 1.0f / nv;
        s1 += inv;
        s2 = fmaf(Ev, inv * inv, s2);
        mb[i] = f2bf(Ev);
        mb[FEATN + i] = f2bf(nv);
    }
    if (lane < KPAD - 2 * FEATN) mb[2 * FEATN + lane] = 0;   // zero pad
    #pragma unroll
    for (int o = 32; o; o >>= 1) { s1 += __shfl_xor(s1, o); s2 += __shfl_xor(s2, o); }
    if (lane == 0) {
        const float np = (float)FEATN / s1;
        cb[26] = np;
        cb[27] = (s2 / (float)FEATN) * np * np;
    }
}

// ---------------- wtrans: W[1002][64]x2 -> Wt[128][1024] bf16 --------------
__global__ __launch_bounds__(256) void wtrans_kernel(
    const float* __restrict__ Bw1, const float* __restrict__ bw1,
    ushort* __restrict__ Wt) {
    const int h = blockIdx.x;
    const int lane = threadIdx.x & 63;
    const int wv = threadIdx.x >> 6;
    const float* W = (h < 64) ? Bw1 : bw1;
    const int col = h & 63;
    #pragma unroll
    for (int it = 0; it < 4; ++it) {
        const int k = it * 256 + wv * 64 + lane;
        const float v = (k < 2 * FEATN) ? W[(size_t)k * 64 + col] : 0.f;
        Wt[(size_t)h * KPAD + k] = f2bf(v);
    }
}

// ---------------- enc: C[16b x 128h] MFMA GEMM, K=1024 ---------------------
__global__ __launch_bounds__(256) void enc_kernel(
    const ushort* __restrict__ Wt,
    const float* __restrict__ Bb1, const float* __restrict__ bb1,
    const float* __restrict__ Bw2, const float* __restrict__ Bb2,
    const float* __restrict__ bw2, const float* __restrict__ bb2,
    float* __restrict__ out) {
    __shared__ ushort Wl[2][4096];
    __shared__ ushort Ml[2][512];
    __shared__ float hid[128][17];
    const int tid = threadIdx.x;
    const int wv = tid >> 6, lane = tid & 63;
    const int bb0 = blockIdx.x * 16;
    float* xi = out + (size_t)NB * NT;

    const int srow = lane >> 2;
    const int sslot = lane & 3;
    const ushort* mbase = (const ushort*)(xi + (size_t)(bb0 + srow) * 4096 + 512);
    const int n0 = wv * 2;

    auto stage = [&](int s, int buf) {
        const int kb = s * 32;
        gl_lds16(Wt + (size_t)(n0 * 16 + srow) * KPAD + kb + sslot * 8,
                 &Wl[buf][n0 * 512]);
        gl_lds16(Wt + (size_t)(n0 * 16 + 16 + srow) * KPAD + kb + sslot * 8,
                 &Wl[buf][n0 * 512 + 512]);
        if (wv == 3) gl_lds16(mbase + kb + sslot * 8, &Ml[buf][0]);
    };

    const int r15 = lane & 15, kg = lane >> 4;
    const int aoff0 = (wv * 32 + r15) * 32 + kg * 8;
    const int aoff1 = aoff0 + 16 * 32;
    const int boff = r15 * 32 + kg * 8;

    f32x4 acc0 = {0.f, 0.f, 0.f, 0.f}, acc1 = acc0;
    stage(0, 0);
    __syncthreads();
    for (int s = 0; s < 32; ++s) {
        const int buf = s & 1;
        if (s + 1 < 32) stage(s + 1, buf ^ 1);
        short8 a0 = *(const short8*)&Wl[buf][aoff0];
        short8 a1 = *(const short8*)&Wl[buf][aoff1];
        short8 b = *(const short8*)&Ml[buf][boff];
        acc0 = __builtin_amdgcn_mfma_f32_16x16x32_bf16(a0, b, acc0, 0, 0, 0);
        acc1 = __builtin_amdgcn_mfma_f32_16x16x32_bf16(a1, b, acc1, 0, 0, 0);
        __syncthreads();
    }

    #pragma unroll
    for (int t = 0; t < 2; ++t) {
        #pragma unroll
        for (int r = 0; r < 4; ++r) {
            const int h = wv * 32 + t * 16 + kg * 4 + r;
            const float bias = (h < 64) ? Bb1[h] : bb1[h - 64];
            float v = (t ? acc1[r] : acc0[r]) + bias;
            v = (h < 64) ? fmaxf(v, 0.f) : softplus_f(v);
            hid[h][r15] = v;
        }
    }
    __syncthreads();

    if (tid < 128) {
        const int bl = tid >> 3, k = tid & 7;
        float dB = 0.f, db = 0.f;
        #pragma unroll 8
        for (int h = 0; h < 64; ++h) {
            dB = fmaf(hid[h][bl], Bw2[h * 8 + k], dB);
            db = fmaf(hid[64 + h][bl], bw2[h * 8 + k], db);
        }
        const float Bm = dB + Bb2[k];
        const float be = softplus_f(db + bb2[k]);
        float Bs = Bm;
        Bs += __shfl_xor(Bs, 1);
        Bs += __shfl_xor(Bs, 2);
        Bs += __shfl_xor(Bs, 4);
        float* cb = xi + (size_t)(bb0 + bl) * 4096;
        const float np = cb[26];
        const float Ep = cb[27];
        cb[k] = 1.f - DTC * be * (Bm + Bs);
        cb[8 + k] = DTC * be * Bm;
        cb[16 + k] = Bm;
        if (k == 0) { cb[24] = Bs * Ep; cb[25] = np; }
    }
}

// ---------------- time loop: LDS-staged inputs, store-only main loop -------
// grid 2048 x 256: one wave per batch. lane = j*8+k.
// Whole per-batch input (e[512], ed[512] = 4 KB) staged to LDS once via
// global_load_lds; the 64-window loop reads only LDS and streams stores.
__global__ __launch_bounds__(256) void time_kernel(
    const float* __restrict__ e, const float* __restrict__ ed,
    const float* coef, float* stress, float* xi_out) {
    __shared__ float els[4][512];
    __shared__ float pls[4][512];
    const int wv = threadIdx.x >> 6;
    const int wid = (blockIdx.x << 2) + wv;
    const int lane = threadIdx.x & 63;
    const int j = lane >> 3, k = lane & 7;

    const float* eb = e + (size_t)wid * NT;
    const float* edb = ed + (size_t)wid * NT;
    // stage this wave's entire input (wave-local: no barrier needed)
    gl_lds16(eb + lane * 4, &els[wv][0]);
    gl_lds16(eb + 256 + lane * 4, &els[wv][256]);
    gl_lds16(edb + lane * 4, &pls[wv][0]);
    gl_lds16(edb + 256 + lane * 4, &pls[wv][256]);

    const float* cb = coef + (size_t)wid * 4096;
    const float a = cb[k];
    const float c = cb[8 + k];
    const float Bm = cb[16 + k];
    const float sE = cb[24];
    const float nup = cb[25];
    // coef loads + LDS staging must land before LDS reads / aliased stores
    asm volatile("s_waitcnt vmcnt(0)" ::: "memory");

    // per-lane window constants:  xi(t0+j) = a^j xi(t0) + sum_{i<j} a^(j-1-i) c u_i
    const float a2 = a * a, a4 = a2 * a2;
    const float P = a4 * a4;                 // a^8
    float A = 1.f;                           // a^j
    if (j & 1) A *= a;
    if (j & 2) A *= a2;
    if (j & 4) A *= a4;
    float pw[8];                             // pw[i] = (i<j) ? a^(j-1-i)*c : 0
    {
        float run = c;
        #pragma unroll
        for (int i = 7; i >= 0; --i) {
            const bool on = (i < j);
            pw[i] = on ? run : 0.f;
            run = on ? run * a : run;
        }
    }
    float pv[8];                             // pv[i] = a^(7-i)*c
    pv[7] = c;
    #pragma unroll
    for (int i = 6; i >= 0; --i) pv[i] = a * pv[i + 1];

    float* xb = xi_out + (size_t)wid * (NT * 8);
    float* sb = stress + (size_t)wid * NT;
    const float* el = &els[wv][0];
    const float* pl = &pls[wv][0];

    // register-pipelined window reads from LDS
    float4 q0 = *(const float4*)(el);
    float4 q1 = *(const float4*)(el + 4);
    float uj = el[j];
    float pj = pl[j];

    float xs = 0.f;
    #pragma unroll 2
    for (int t0 = 0; t0 < NT; t0 += 8) {
        const float u0 = q0.x, u1 = q0.y, u2 = q0.z, u3 = q0.w;
        const float u4 = q1.x, u5 = q1.y, u6 = q1.z, u7 = q1.w;
        const float cuj = uj, cpj = pj;
        if (t0 + 8 < NT) {                   // prefetch next window (LDS)
            q0 = *(const float4*)(el + t0 + 8);
            q1 = *(const float4*)(el + t0 + 12);
            uj = el[t0 + 8 + j];
            pj = pl[t0 + 8 + j];
        }
        float xi_j = A * xs;
        xi_j = fmaf(pw[0], u0, xi_j);
        xi_j = fmaf(pw[1], u1, xi_j);
        xi_j = fmaf(pw[2], u2, xi_j);
        xi_j = fmaf(pw[3], u3, xi_j);
        xi_j = fmaf(pw[4], u4, xi_j);
        xi_j = fmaf(pw[5], u5, xi_j);
        xi_j = fmaf(pw[6], u6, xi_j);
        xi_j = fmaf(pw[7], u7, xi_j);
        float ns = P * xs;
        ns = fmaf(pv[0], u0, ns);
        ns = fmaf(pv[1], u1, ns);
        ns = fmaf(pv[2], u2, ns);
        ns = fmaf(pv[3], u3, ns);
        ns = fmaf(pv[4], u4, ns);
        ns = fmaf(pv[5], u5, ns);
        ns = fmaf(pv[6], u6, ns);
        ns = fmaf(pv[7], u7, ns);
        xs = ns;
        xb[t0 * 8 + lane] = xi_j;            // coalesced 256B/wave
        float r = Bm * (cuj - xi_j);
        r = dpp_add(r, 0xB1);                // + lane^1
        r = dpp_add(r, 0x4E);                // + lane^2
        r = dpp_add(r, 0x141);               // + other quad (within 8)
        if (k == 0) sb[t0 + j] = fmaf(sE, cuj, fmaf(nup, cpj, r));
    }
}

extern "C" void kernel_launch(void* const* d_in, const int* in_sizes, int n_in,
                              void* d_out, int out_size, void* d_ws, size_t ws_size,
                              hipStream_t stream) {
    const float* e   = (const float*)d_in[0];
    const float* ed  = (const float*)d_in[1];
    const float* E   = (const float*)d_in[2];
    const float* nu  = (const float*)d_in[3];
    const float* Bw1 = (const float*)d_in[4];
    const float* Bb1 = (const float*)d_in[5];
    const float* Bw2 = (const float*)d_in[6];
    const float* Bb2 = (const float*)d_in[7];
    const float* bw1 = (const float*)d_in[8];
    const float* bb1 = (const float*)d_in[9];
    const float* bw2 = (const float*)d_in[10];
    const float* bb2 = (const float*)d_in[11];

    float* out = (float*)d_out;
    float* stress = out;                        // [B*T] floats
    float* xi = out + (size_t)NB * NT;          // [B*T*8] floats
    ushort* Wt = (ushort*)out;                  // 256 KB stash in stress region

    prep_kernel<<<2048, 256, 0, stream>>>(E, nu, out);
    wtrans_kernel<<<128, 256, 0, stream>>>(Bw1, bw1, Wt);
    enc_kernel<<<512, 256, 0, stream>>>(Wt, Bb1, bb1, Bw2, Bb2, bw2, bb2, out);
    time_kernel<<<2048, 256, 0, stream>>>(e, ed, xi, stress, xi);
}